// Round 5
// baseline (621.638 us; speedup 1.0000x reference)
//
#include <hip/hip_runtime.h>
#include <hip/hip_bf16.h>

namespace {
constexpr int kN    = 50000;
constexpr int kE    = 800000;
constexpr int kEtot = kE + kN;   // 850000 (self-loops appended)
constexpr int kEd   = 16;
constexpr int kH    = 8;
constexpr int kD    = 32;
constexpr int kC    = kH * kD;   // 256
constexpr int kNM   = 500;
constexpr int kNB   = (kN + 255) / 256;  // 196 scan blocks
constexpr int kCap  = 128;               // LDS softmax capacity (max deg ~45 here)
}

typedef __attribute__((ext_vector_type(8))) _Float16 half8;
typedef __attribute__((ext_vector_type(4))) float floatx4;

__device__ __forceinline__ float h2f(ushort u) {
  union { ushort u; _Float16 h; } v;
  v.u = u;
  return (float)v.h;
}
__device__ __forceinline__ ushort f2h(float f) {
  union { _Float16 h; ushort u; } v;
  v.h = (_Float16)f;  // v_cvt_f16_f32, RNE
  return v.u;
}

// ---------------- fused preprocessing: fp16 conversions + deg count + Q3 ----------------
// deg must be zeroed (hipMemsetAsync) before this launch.
__global__ void gat_pre(const float* __restrict__ x,
                        const float* __restrict__ W1, const float* __restrict__ W2,
                        const float* __restrict__ W3, const float* __restrict__ lw1,
                        const float* __restrict__ lw2,
                        ushort* __restrict__ xh, ushort* __restrict__ Wt1,
                        ushort* __restrict__ Wt2, ushort* __restrict__ Wt3,
                        ushort* __restrict__ lwt1, ushort* __restrict__ lwt2p,
                        const int* __restrict__ ei, int* __restrict__ deg,
                        const float* __restrict__ We1, const float* __restrict__ ae1,
                        const float* __restrict__ We2, const float* __restrict__ ae2,
                        const float* __restrict__ We3, const float* __restrict__ ae3,
                        float* __restrict__ Q3) {
  int i = blockIdx.x * blockDim.x + threadIdx.x;
  if (i < kN * 64) { xh[i] = f2h(x[i]); return; }
  i -= kN * 64;
  if (i < 256 * 64) {  // Wt1[n][k], W1 is 64x256
    int n = i >> 6, k = i & 63;
    Wt1[i] = f2h(W1[(long)k * 256 + n]);
    return;
  }
  i -= 256 * 64;
  if (i < 256 * 256) {
    int n = i >> 8, k = i & 255;
    Wt2[i] = f2h(W2[(long)k * 256 + n]);
    return;
  }
  i -= 256 * 256;
  if (i < 256 * 256) {
    int n = i >> 8, k = i & 255;
    Wt3[i] = f2h(W3[(long)k * 256 + n]);
    return;
  }
  i -= 256 * 256;
  if (i < 96 * 1024) {  // lwt1[n][k], lw1 is 1024x96
    int n = i >> 10, k = i & 1023;
    lwt1[i] = f2h(lw1[(long)k * 96 + n]);
    return;
  }
  i -= 96 * 1024;
  if (i < 64 * 128) {  // lwt2p[n][k], K zero-padded 96->128; lw2 is 96x64
    int n = i >> 7, k = i & 127;
    lwt2p[i] = (k < 96) ? f2h(lw2[(long)k * 64 + n]) : (ushort)0;
    return;
  }
  i -= 64 * 128;
  if (i < kE) {  // degree count
    atomicAdd(&deg[ei[kE + i]], 1);
    return;
  }
  i -= kE;
  if (i < 384) {  // Q3[l][c][h] = sum_d We_l[c, h*32+d] * ae_l[h,d]
    int l = i >> 7, r = i & 127;
    const float* We = (l == 0) ? We1 : (l == 1) ? We2 : We3;
    const float* ae = (l == 0) ? ae1 : (l == 1) ? ae2 : ae3;
    int c = r >> 3, h = r & 7;
    float s = 0.f;
#pragma unroll
    for (int d = 0; d < kD; d++) s += We[c * kC + h * kD + d] * ae[h * kD + d];
    Q3[l * 128 + c * kH + h] = s;
  }
}

// ---------------- CSR build (shared by all 3 layers) ----------------
// hierarchical scan of (deg[i]+1); also zeroes fillc (used later by gat_fill)
__global__ __launch_bounds__(256) void gat_scan_a(const int* __restrict__ deg,
                                                  int* __restrict__ offs,
                                                  int* __restrict__ bsum,
                                                  int* __restrict__ fillc) {
  __shared__ int s[256];
  int b = blockIdx.x, t = threadIdx.x;
  int i = b * 256 + t;
  int v = (i < kN) ? deg[i] + 1 : 0;
  if (i < kN) fillc[i] = 0;
  s[t] = v;
  __syncthreads();
  for (int o = 1; o < 256; o <<= 1) {
    int u = (t >= o) ? s[t - o] : 0;
    __syncthreads();
    s[t] += u;
    __syncthreads();
  }
  if (i < kN) offs[i] = s[t] - v;
  if (t == 255) bsum[b] = s[255];
}

// merged scan_b + scan_c: every block redundantly scans the 196 block sums (cheap),
// takes its own exclusive prefix, applies it to its 256 offs entries.
__global__ __launch_bounds__(256) void gat_scan_bc(int* __restrict__ offs,
                                                   const int* __restrict__ bsum) {
  __shared__ int s[256];
  int t = threadIdx.x;
  int v = (t < kNB) ? bsum[t] : 0;
  s[t] = v;
  __syncthreads();
  for (int o = 1; o < 256; o <<= 1) {
    int u = (t >= o) ? s[t - o] : 0;
    __syncthreads();
    s[t] += u;
    __syncthreads();
  }
  int excl = s[t] - v;
  __syncthreads();
  s[t] = excl;
  __syncthreads();
  int pre = s[blockIdx.x];
  int i = blockIdx.x * 256 + t;
  if (i < kN) offs[i] += pre;
  if (i == 0) offs[kN] = kEtot;
}

// CSR fill: el[pos]=edge id; esrc[pos]=src; sposA[n]=self-loop pos.
// (Scatter writes are 4B -- small; the 16B aq writes are done STREAMING in gat_aq.)
__global__ void gat_fill(const int* __restrict__ ei, const int* __restrict__ offs,
                         int* __restrict__ fillc, int* __restrict__ el,
                         int* __restrict__ esrc, int* __restrict__ sposA) {
  int e = blockIdx.x * blockDim.x + threadIdx.x;
  if (e >= kEtot) return;
  int s, d;
  if (e < kE) { s = ei[e]; d = ei[kE + e]; }
  else { s = d = e - kE; }
  int pos = offs[d] + atomicAdd(&fillc[d], 1);
  el[pos] = e;
  esrc[pos] = s;
  if (e >= kE) sposA[e - kE] = pos;
}

// aqX[pos*8+h] = ea[el[pos]] . Q_l[:,h]  for l=0..2 (CSR-ordered planes, fp16).
// Thread = pos (STREAMING writes); ea read is a random 64B-line gather (no amplification).
// Self-loop slots get 0 (aggregate folds in the segment sum -- linearity of the dot).
__global__ __launch_bounds__(256) void gat_aq(const int* __restrict__ el,
                                              const float* __restrict__ ea,
                                              const float* __restrict__ Q3,
                                              ushort* __restrict__ aq0,
                                              ushort* __restrict__ aq1,
                                              ushort* __restrict__ aq2) {
  __shared__ float Qs[384];
  int t = threadIdx.x;
  for (int i = t; i < 384; i += 256) Qs[i] = Q3[i];
  __syncthreads();
  int pos = blockIdx.x * blockDim.x + t;
  if (pos >= kEtot) return;
  int e = el[pos];
  long base = (long)pos * kH;
  if (e >= kE) {
    uint4 z = {0u, 0u, 0u, 0u};
    *(uint4*)(aq0 + base) = z;
    *(uint4*)(aq1 + base) = z;
    *(uint4*)(aq2 + base) = z;
    return;
  }
  float eav[kEd];
#pragma unroll
  for (int q = 0; q < kEd / 4; q++) {
    float4 v = *(const float4*)(ea + (long)e * kEd + q * 4);
    eav[q * 4 + 0] = v.x; eav[q * 4 + 1] = v.y;
    eav[q * 4 + 2] = v.z; eav[q * 4 + 3] = v.w;
  }
  ushort* outp[3] = {aq0, aq1, aq2};
#pragma unroll
  for (int l = 0; l < 3; l++) {
    union { uint4 u; ushort us[8]; } o;
#pragma unroll
    for (int h = 0; h < kH; h++) {
      float q = 0.f;
#pragma unroll
      for (int c = 0; c < kEd; c++) q += eav[c] * Qs[l * 128 + c * kH + h];
      o.us[h] = f2h(q);
    }
    *(uint4*)(outp[l] + base) = o.u;
  }
}

// ---------------- fp16 MFMA GEMM (64M x 128N tile) ----------------
// Ch fp16 <- A(MxK,fp16 row-major) @ Bt^T  (layer GEMMs; always COEF epilogue)
// COEF: emit a_src[row,h]=xl_row_h . as_[h], a_dst likewise (N=256; 4 heads/block).
__global__ __launch_bounds__(256) void gat_gemm_mfma(
    int M, int K,
    const ushort* __restrict__ A0,
    const ushort* __restrict__ Bt,
    ushort* __restrict__ Ch, int ldch,
    const float* __restrict__ as_, const float* __restrict__ ad_,
    float* __restrict__ a_src, float* __restrict__ a_dst) {
  __shared__ ushort As[8][64][8];   // 8 KB
  __shared__ ushort Bs[8][128][8];  // 16 KB
  int t = threadIdx.x;
  int rowBase = blockIdx.y * 64;
  int colBase = blockIdx.x * 128;
  int w = t >> 6, L = t & 63;

  floatx4 acc[8];
#pragma unroll
  for (int i = 0; i < 8; i++) acc[i] = (floatx4){0.f, 0.f, 0.f, 0.f};

  int ar = t >> 2, akq = t & 3;  // A staging: row 0..63, k-chunk base
  int arow = rowBase + ar;
  int bn = t >> 1, bq2 = (t & 1) * 4;  // B staging: n 0..127, chunk half
  long brow = (long)(colBase + bn) * K;

  for (int k0 = 0; k0 < K; k0 += 64) {
#pragma unroll
    for (int half = 0; half < 2; half++) {
      int q = akq + half * 4;
      int gk = k0 + q * 8;
      uint4 av = {0u, 0u, 0u, 0u};
      if (arow < M) av = *(const uint4*)(A0 + (long)arow * K + gk);
      *(uint4*)&As[q][ar][0] = av;
    }
#pragma unroll
    for (int u = 0; u < 4; u++) {
      int q = bq2 + u;
      uint4 bv = *(const uint4*)(Bt + brow + k0 + q * 8);
      *(uint4*)&Bs[q][bn][0] = bv;
    }
    __syncthreads();
    int mrow = w * 16 + (L & 15);
    int nl = L & 15;
#pragma unroll
    for (int half = 0; half < 2; half++) {
      int q = (L >> 4) + half * 4;
      half8 af = *(const half8*)&As[q][mrow][0];
#pragma unroll
      for (int t8 = 0; t8 < 8; t8++) {
        half8 bf = *(const half8*)&Bs[q][t8 * 16 + nl][0];
        acc[t8] = __builtin_amdgcn_mfma_f32_16x16x32_f16(af, bf, acc[t8], 0, 0, 0);
      }
    }
    __syncthreads();
  }
  int nlo = L & 15;
  int rbase = rowBase + w * 16 + (L >> 4) * 4;
#pragma unroll
  for (int t8 = 0; t8 < 8; t8++) {
    int col = colBase + t8 * 16 + nlo;
#pragma unroll
    for (int r = 0; r < 4; r++) {
      int row = rbase + r;
      if (row >= M) continue;
      Ch[(long)row * ldch + col] = f2h(acc[t8][r]);
    }
  }
  {
    float ps[4][4], pd[4][4];
#pragma unroll
    for (int g = 0; g < 4; g++)
#pragma unroll
      for (int r = 0; r < 4; r++) { ps[g][r] = 0.f; pd[g][r] = 0.f; }
    int hA = colBase >> 5;
#pragma unroll
    for (int t8 = 0; t8 < 8; t8++) {
      int g = t8 >> 1;
      int widx = (t8 & 1) * 16 + nlo;
      float wsv = as_[(hA + g) * kD + widx];
      float wdv = ad_[(hA + g) * kD + widx];
#pragma unroll
      for (int r = 0; r < 4; r++) {
        ps[g][r] += acc[t8][r] * wsv;
        pd[g][r] += acc[t8][r] * wdv;
      }
    }
#pragma unroll
    for (int m = 1; m < 16; m <<= 1) {
#pragma unroll
      for (int g = 0; g < 4; g++)
#pragma unroll
        for (int r = 0; r < 4; r++) {
          ps[g][r] += __shfl_xor(ps[g][r], m);
          pd[g][r] += __shfl_xor(pd[g][r], m);
        }
    }
    if (nlo == 0) {
#pragma unroll
      for (int r = 0; r < 4; r++) {
        int row = rbase + r;
        if (row >= M) continue;
#pragma unroll
        for (int g = 0; g < 4; g++) {
          a_src[row * kH + hA + g] = ps[g][r];
          a_dst[row * kH + hA + g] = pd[g][r];
        }
      }
    }
  }
}

// ---------------- fused logits + segment-softmax + aggregation ----------------
// one wave per node. Logit a = leaky(a_src[src,h] + a_dst[n,h] + aq[pos,h]).
// Self-loop aq (= segment sum of aq, via linearity) is folded in here: aq self slots
// hold 0, phase 1 accumulates sq = sum_j aq[j,h] and fixes the self slot's logit.
__global__ __launch_bounds__(256, 8) void gat_aggregate(
    const int* __restrict__ offs, const int* __restrict__ esrc,
    const int* __restrict__ sposA,
    const ushort* __restrict__ aq,
    const float* __restrict__ a_src, const float* __restrict__ a_dst,
    const ushort* __restrict__ xlh, const float* __restrict__ bias,
    ushort* __restrict__ hh) {
  __shared__ float alf[4][kCap][kH];  // 16 KB
  __shared__ int srcs[4][kCap];       // 2 KB
  int wid = threadIdx.x >> 6;
  int n = blockIdx.x * 4 + wid;  // grid is exact: kN % 4 == 0
  int L = threadIdx.x & 63;
  int lo = offs[n], hi = offs[n + 1];
  int deg = hi - lo;
  bool fits = (deg <= kCap);
  int spos = sposA[n];  // CSR position of n's self-loop
  int hp = L & 7, sl = L >> 3;
  float adr = a_dst[n * kH + hp];
  float m = -1e30f;
  float sq = 0.f;
  if (fits) {
    for (int j = lo + sl; j < hi; j += 8) {
      int sidx = esrc[j];
      float aqv = h2f(aq[(long)j * kH + hp]);
      sq += aqv;
      float a = a_src[sidx * kH + hp] + adr + aqv;
      a = a > 0.f ? a : 0.2f * a;
      alf[wid][j - lo][hp] = a;
      if (hp == 0) srcs[wid][j - lo] = sidx;
      m = fmaxf(m, a);
    }
  } else {
    for (int j = lo + sl; j < hi; j += 8) {
      float aqv = h2f(aq[(long)j * kH + hp]);
      sq += aqv;
      float a = a_src[esrc[j] * kH + hp] + adr + aqv;
      a = a > 0.f ? a : 0.2f * a;
      m = fmaxf(m, a);
    }
  }
#pragma unroll
  for (int msk = 8; msk < 64; msk <<= 1) {
    m = fmaxf(m, __shfl_xor(m, msk));
    sq += __shfl_xor(sq, msk);
  }
  // self-loop logit: src = n, aq_self = sq (self slot held 0, so sq is the edge sum)
  float aself = a_src[n * kH + hp] + adr + sq;
  aself = aself > 0.f ? aself : 0.2f * aself;
  m = fmaxf(m, aself);
  if (fits && sl == 0) alf[wid][spos - lo][hp] = aself;  // same-wave overwrite, ordered
  __syncthreads();
  float s = 0.f;
  if (fits) {
    for (int j = lo + sl; j < hi; j += 8) {
      float pp = __expf(alf[wid][j - lo][hp] - m);
      alf[wid][j - lo][hp] = pp;
      s += pp;
    }
  } else {
    for (int j = lo + sl; j < hi; j += 8) {
      float aqv = (j == spos) ? sq : h2f(aq[(long)j * kH + hp]);
      float a = a_src[esrc[j] * kH + hp] + adr + aqv;
      a = a > 0.f ? a : 0.2f * a;
      s += __expf(a - m);
    }
  }
#pragma unroll
  for (int msk = 8; msk < 64; msk <<= 1) s += __shfl_xor(s, msk);
  __syncthreads();
  // ---- main: half-wave per edge, 4 edges x 2 half-waves per iter ----
  int eh = L >> 5;
  int cl = L & 31;
  int c = cl * 8;
  int h = cl >> 2;
  float invs = 1.f / __shfl(s, h);
  float mh = __shfl(m, h);
  float acc[8] = {0.f, 0.f, 0.f, 0.f, 0.f, 0.f, 0.f, 0.f};
  union { uint4 u; _Float16 hf[8]; } v0, v1, v2, v3;
  if (fits) {
    int j = lo;
    for (; j + 8 <= hi; j += 8) {
      int j0 = j + eh, j1 = j + 2 + eh, j2 = j + 4 + eh, j3 = j + 6 + eh;
      int s0 = srcs[wid][j0 - lo];
      int s1 = srcs[wid][j1 - lo];
      int s2 = srcs[wid][j2 - lo];
      int s3 = srcs[wid][j3 - lo];
      float t0 = alf[wid][j0 - lo][h];
      float t1 = alf[wid][j1 - lo][h];
      float t2 = alf[wid][j2 - lo][h];
      float t3 = alf[wid][j3 - lo][h];
      v0.u = *(const uint4*)(xlh + (long)s0 * kC + c);
      v1.u = *(const uint4*)(xlh + (long)s1 * kC + c);
      v2.u = *(const uint4*)(xlh + (long)s2 * kC + c);
      v3.u = *(const uint4*)(xlh + (long)s3 * kC + c);
#pragma unroll
      for (int i = 0; i < 8; i++) acc[i] += t0 * (float)v0.hf[i];
#pragma unroll
      for (int i = 0; i < 8; i++) acc[i] += t1 * (float)v1.hf[i];
#pragma unroll
      for (int i = 0; i < 8; i++) acc[i] += t2 * (float)v2.hf[i];
#pragma unroll
      for (int i = 0; i < 8; i++) acc[i] += t3 * (float)v3.hf[i];
    }
    for (; j < hi; j += 2) {
      int jj = j + eh;
      bool valid = jj < hi;
      int idx = valid ? jj - lo : 0;
      int sn = srcs[wid][idx];
      float att = valid ? alf[wid][idx][h] : 0.f;
      v0.u = *(const uint4*)(xlh + (long)sn * kC + c);
#pragma unroll
      for (int i = 0; i < 8; i++) acc[i] += att * (float)v0.hf[i];
    }
  } else {
    float adh = a_dst[n * kH + h];
    float sqh = __shfl(sq, h);
    for (int j = lo; j < hi; j += 2) {
      int jj = j + eh;
      bool valid = jj < hi;
      int js = valid ? jj : lo;
      int sn = esrc[js];
      float aqv = (js == spos) ? sqh : h2f(aq[(long)js * kH + h]);
      float a = a_src[sn * kH + h] + adh + aqv;
      a = a > 0.f ? a : 0.2f * a;
      float att = valid ? __expf(a - mh) : 0.f;
      v0.u = *(const uint4*)(xlh + (long)sn * kC + c);
#pragma unroll
      for (int i = 0; i < 8; i++) acc[i] += att * (float)v0.hf[i];
    }
  }
#pragma unroll
  for (int i = 0; i < 8; i++) acc[i] += __shfl_xor(acc[i], 32);
  if (eh == 0) {
    float4 b0 = *(const float4*)(bias + c);
    float4 b1 = *(const float4*)(bias + c + 4);
    ushort o[8];
    o[0] = f2h(acc[0] * invs + b0.x); o[1] = f2h(acc[1] * invs + b0.y);
    o[2] = f2h(acc[2] * invs + b0.z); o[3] = f2h(acc[3] * invs + b0.w);
    o[4] = f2h(acc[4] * invs + b1.x); o[5] = f2h(acc[5] * invs + b1.y);
    o[6] = f2h(acc[6] * invs + b1.z); o[7] = f2h(acc[7] * invs + b1.w);
    *(uint4*)(hh + (long)n * kC + c) = *(uint4*)o;
  }
}

// ---------------- pooling: 1024 threads = 4 row-groups x 256 channels ----------------
__global__ __launch_bounds__(1024) void gat_pool(const ushort* __restrict__ h3h,
                                                 const int* __restrict__ batch,
                                                 ushort* __restrict__ hpoolh) {
  __shared__ float red[3][256];
  int m = blockIdx.x;
  int c = threadIdx.x & 255;
  int g = threadIdx.x >> 8;  // 0..3
  int lo = 0, hi = kN;
  while (lo < hi) { int mid = (lo + hi) >> 1; if (batch[mid] < m) lo = mid + 1; else hi = mid; }
  int start = lo;
  hi = kN;
  while (lo < hi) { int mid = (lo + hi) >> 1; if (batch[mid] < m + 1) lo = mid + 1; else hi = mid; }
  int end = lo;
  float s0 = 0.f, s1 = 0.f, s2 = 0.f, s3 = 0.f;
  int n = start + g;
  for (; n + 12 < end; n += 16) {
    s0 += h2f(h3h[(long)n * kC + c]);
    s1 += h2f(h3h[(long)(n + 4) * kC + c]);
    s2 += h2f(h3h[(long)(n + 8) * kC + c]);
    s3 += h2f(h3h[(long)(n + 12) * kC + c]);
  }
  for (; n < end; n += 4) s0 += h2f(h3h[(long)n * kC + c]);
  float s = (s0 + s1) + (s2 + s3);
  if (g > 0) red[g - 1][c] = s;
  __syncthreads();
  if (g == 0)
    hpoolh[(long)m * kC + c] = f2h(s + red[0][c] + red[1][c] + red[2][c]);
}

// ---------------- fused 3-stage MLP ----------------
// stage1: leaky( concat[h1,h2,h3,hpool[batch]] @ lwt1^T + lb1 ) -> C1s (LDS, fp16, 64x128, cols 96+ = 0)
// stage2: leaky( C1s @ lwt2p^T + lb2 ), dot with lw3, + lb3, sigmoid -> out[row]
__global__ __launch_bounds__(256) void gat_mlp(
    const ushort* __restrict__ h1h, const ushort* __restrict__ h2h,
    const ushort* __restrict__ h3h, const ushort* __restrict__ hpoolh,
    const int* __restrict__ batch,
    const ushort* __restrict__ lwt1, const float* __restrict__ lb1,
    const ushort* __restrict__ lwt2p, const float* __restrict__ lb2,
    const float* __restrict__ lw3, const float* __restrict__ lb3,
    float* __restrict__ out) {
  __shared__ ushort As[8][64][8];    // 8 KB
  __shared__ ushort Bs[8][128][8];   // 16 KB
  __shared__ ushort C1s[16][64][8];  // 16 KB: stage-1 out, chunk-major [q][row][k&7]
  __shared__ ushort B2s[16][64][8];  // 16 KB: lwt2p staged, [q][n][k&7]
  constexpr int K = 1024;
  int t = threadIdx.x;
  int rowBase = blockIdx.x * 64;
  int w = t >> 6, L = t & 63;

  floatx4 acc[8];
#pragma unroll
  for (int i = 0; i < 8; i++) acc[i] = (floatx4){0.f, 0.f, 0.f, 0.f};

  int ar = t >> 2, akq = t & 3;
  int arow = rowBase + ar;
  int bn = t >> 1, bq2 = (t & 1) * 4;
  bool bok = bn < 96;
  long brow = (long)bn * K;

  for (int k0 = 0; k0 < K; k0 += 64) {
#pragma unroll
    for (int half = 0; half < 2; half++) {
      int q = akq + half * 4;
      int gk = k0 + q * 8;
      uint4 av = {0u, 0u, 0u, 0u};
      if (arow < kN) {
        int j = gk >> 8, kc = gk & 255;
        const ushort* src = (j == 0) ? h1h : (j == 1) ? h2h : (j == 2) ? h3h : hpoolh;
        long rr = (j == 3) ? (long)batch[arow] : (long)arow;
        av = *(const uint4*)(src + rr * 256 + kc);
      }
      *(uint4*)&As[q][ar][0] = av;
    }
#pragma unroll
    for (int u = 0; u < 4; u++) {
      int q = bq2 + u;
      uint4 bv = {0u, 0u, 0u, 0u};
      if (bok) bv = *(const uint4*)(lwt1 + brow + k0 + q * 8);
      *(uint4*)&Bs[q][bn][0] = bv;
    }
    __syncthreads();
    int mrow = w * 16 + (L & 15);
    int nl = L & 15;
#pragma unroll
    for (int half = 0; half < 2; half++) {
      int q = (L >> 4) + half * 4;
      half8 af = *(const half8*)&As[q][mrow][0];
#pragma unroll
      for (int t8 = 0; t8 < 8; t8++) {
        half8 bf = *(const half8*)&Bs[q][t8 * 16 + nl][0];
        acc[t8] = __builtin_amdgcn_mfma_f32_16x16x32_f16(af, bf, acc[t8], 0, 0, 0);
      }
    }
    __syncthreads();
  }
  // stage-1 epilogue -> C1s (local rows 0..63). cols >= 96 have acc==0, lb1 treated 0 -> stays 0.
  int nlo = L & 15;
  int lrbase = w * 16 + (L >> 4) * 4;
#pragma unroll
  for (int t8 = 0; t8 < 8; t8++) {
    int col = t8 * 16 + nlo;  // 0..127
    float bv = (col < 96) ? lb1[col] : 0.f;
#pragma unroll
    for (int r = 0; r < 4; r++) {
      float v = acc[t8][r] + bv;
      v = v > 0.f ? v : 0.01f * v;
      C1s[col >> 3][lrbase + r][col & 7] = f2h(v);
    }
  }
  // stage-2 B: lwt2p is [64 n][128 k]
  {
    int n2 = t >> 2, u0 = (t & 3) * 4;
#pragma unroll
    for (int u = 0; u < 4; u++) {
      int q = u0 + u;
      *(uint4*)&B2s[q][n2][0] = *(const uint4*)(lwt2p + (long)n2 * 128 + q * 8);
    }
  }
  __syncthreads();
  // stage-2 MFMA: 64 rows x 64 cols, K=128 in 4 K-32 steps.
  // FRAGMENT LAYOUT: lane-group (L>>4) must hold k-chunk (L>>4)+ks*4 -- same as stage 1.
  floatx4 acc2[4];
#pragma unroll
  for (int i = 0; i < 4; i++) acc2[i] = (floatx4){0.f, 0.f, 0.f, 0.f};
  {
    int mrow = w * 16 + (L & 15);
    int nl = L & 15;
#pragma unroll
    for (int ks = 0; ks < 4; ks++) {
      int q = (L >> 4) + ks * 4;
      half8 af = *(const half8*)&C1s[q][mrow][0];
#pragma unroll
      for (int nf = 0; nf < 4; nf++) {
        half8 bf = *(const half8*)&B2s[q][nf * 16 + nl][0];
        acc2[nf] = __builtin_amdgcn_mfma_f32_16x16x32_f16(af, bf, acc2[nf], 0, 0, 0);
      }
    }
  }
  // stage-2 epilogue: leaky(.+lb2) . lw3 + lb3 -> sigmoid -> out
  {
    float dot[4] = {0.f, 0.f, 0.f, 0.f};
#pragma unroll
    for (int nf = 0; nf < 4; nf++) {
      int col = nf * 16 + nlo;  // 0..63
      float bv = lb2[col];
      float wv = lw3[col];
#pragma unroll
      for (int r = 0; r < 4; r++) {
        float v = acc2[nf][r] + bv;
        v = v > 0.f ? v : 0.01f * v;
        dot[r] += v * wv;
      }
    }
#pragma unroll
    for (int msk = 1; msk < 16; msk <<= 1)
#pragma unroll
      for (int r = 0; r < 4; r++) dot[r] += __shfl_xor(dot[r], msk);
    if (nlo == 0) {
      float b3 = lb3[0];
#pragma unroll
      for (int r = 0; r < 4; r++) {
        int row = rowBase + lrbase + r;
        if (row < kN) out[row] = 1.f / (1.f + __expf(-(dot[r] + b3)));
      }
    }
  }
}

// ---------------- host ----------------
static inline int cdiv(int a, int b) { return (a + b - 1) / b; }

extern "C" void kernel_launch(void* const* d_in, const int* in_sizes, int n_in,
                              void* d_out, int out_size, void* d_ws, size_t ws_size,
                              hipStream_t stream) {
  (void)in_sizes; (void)n_in; (void)out_size; (void)ws_size;
  const float* x = (const float*)d_in[0];
  const int* ei = (const int*)d_in[1];
  const float* ea = (const float*)d_in[2];
  const int* batch = (const int*)d_in[3];
  const float *W[3], *as_[3], *ad_[3], *We_[3], *ae_[3], *bb[3];
  for (int l = 0; l < 3; l++) {
    W[l]   = (const float*)d_in[4 + 6 * l];
    as_[l] = (const float*)d_in[5 + 6 * l];
    ad_[l] = (const float*)d_in[6 + 6 * l];
    We_[l] = (const float*)d_in[7 + 6 * l];
    ae_[l] = (const float*)d_in[8 + 6 * l];
    bb[l]  = (const float*)d_in[9 + 6 * l];
  }
  const float* lw1 = (const float*)d_in[22];
  const float* lb1 = (const float*)d_in[23];
  const float* lw2 = (const float*)d_in[24];
  const float* lb2 = (const float*)d_in[25];
  const float* lw3 = (const float*)d_in[26];
  const float* lb3 = (const float*)d_in[27];
  float* out = (float*)d_out;

  char* p = (char*)d_ws;
  auto carve = [&](size_t bytes) -> void* {
    void* r = (void*)p;
    p += (bytes + 255) & ~(size_t)255;
    return r;
  };
  ushort* aq0    = (ushort*)carve(sizeof(ushort) * (size_t)kEtot * kH);
  ushort* aq1    = (ushort*)carve(sizeof(ushort) * (size_t)kEtot * kH);
  ushort* aq2    = (ushort*)carve(sizeof(ushort) * (size_t)kEtot * kH);
  float* a_src   = (float*)carve(sizeof(float) * (size_t)kN * kH);
  float* a_dst   = (float*)carve(sizeof(float) * (size_t)kN * kH);
  float* Q3      = (float*)carve(sizeof(float) * 3 * 128);
  ushort* xh     = (ushort*)carve(sizeof(ushort) * (size_t)kN * 64);
  ushort* xlh    = (ushort*)carve(sizeof(ushort) * (size_t)kN * kC);
  ushort* h1h    = (ushort*)carve(sizeof(ushort) * (size_t)kN * kC);
  ushort* h2h    = (ushort*)carve(sizeof(ushort) * (size_t)kN * kC);
  ushort* h3h    = (ushort*)carve(sizeof(ushort) * (size_t)kN * kC);
  ushort* hpoolh = (ushort*)carve(sizeof(ushort) * (size_t)kNM * kC);
  ushort* Wt1    = (ushort*)carve(sizeof(ushort) * 64 * 256);
  ushort* Wt2    = (ushort*)carve(sizeof(ushort) * 256 * 256);
  ushort* Wt3    = (ushort*)carve(sizeof(ushort) * 256 * 256);
  ushort* lwt1   = (ushort*)carve(sizeof(ushort) * 1024 * 96);
  ushort* lwt2p  = (ushort*)carve(sizeof(ushort) * 64 * 128);
  int* deg   = (int*)carve(sizeof(int) * kN);
  int* fillc = (int*)carve(sizeof(int) * kN);
  int* offs  = (int*)carve(sizeof(int) * (kN + 1));
  int* bsum  = (int*)carve(sizeof(int) * 256);
  int* el    = (int*)carve(sizeof(int) * kEtot);
  int* esrc  = (int*)carve(sizeof(int) * kEtot);
  int* sposA = (int*)carve(sizeof(int) * kN);

  // ---- zero deg (driver-side) + fused conversions/count/Q ----
  hipMemsetAsync(deg, 0, sizeof(int) * kN, stream);
  {
    int tot = kN * 64 + 256 * 64 + 2 * 256 * 256 + 96 * 1024 + 64 * 128 + kE + 384;
    gat_pre<<<cdiv(tot, 256), 256, 0, stream>>>(
        x, W[0], W[1], W[2], lw1, lw2, xh, Wt1, Wt2, Wt3, lwt1, lwt2p,
        ei, deg, We_[0], ae_[0], We_[1], ae_[1], We_[2], ae_[2], Q3);
  }

  // ---- CSR build + edge-coefficient precompute (all 3 layers at once) ----
  gat_scan_a<<<kNB, 256, 0, stream>>>(deg, offs, bsum, fillc);
  gat_scan_bc<<<kNB, 256, 0, stream>>>(offs, bsum);
  gat_fill<<<cdiv(kEtot, 256), 256, 0, stream>>>(ei, offs, fillc, el, esrc, sposA);
  gat_aq<<<cdiv(kEtot, 256), 256, 0, stream>>>(el, ea, Q3, aq0, aq1, aq2);

  // ---- 3 GAT layers ----
  const ushort* hinh[3] = {xh, h1h, h2h};
  ushort* houth[3] = {h1h, h2h, h3h};
  const ushort* Wt[3] = {Wt1, Wt2, Wt3};
  const ushort* aqP[3] = {aq0, aq1, aq2};
  int kdim[3] = {64, kC, kC};
  for (int l = 0; l < 3; l++) {
    dim3 ggrid(kC / 128, cdiv(kN, 64));
    gat_gemm_mfma<<<ggrid, 256, 0, stream>>>(
        kN, kdim[l], hinh[l], Wt[l], xlh, kC,
        as_[l], ad_[l], a_src, a_dst);
    gat_aggregate<<<kN / 4, 256, 0, stream>>>(offs, esrc, sposA, aqP[l], a_src, a_dst,
                                              xlh, bb[l], houth[l]);
  }

  // ---- pooling ----
  gat_pool<<<kNM, 1024, 0, stream>>>(h3h, batch, hpoolh);

  // ---- fused MLP (all 3 layers + sigmoid, one launch) ----
  gat_mlp<<<cdiv(kN, 64), 256, 0, stream>>>(
      h1h, h2h, h3h, hpoolh, batch,
      lwt1, lb1, lwt2p, lb2, lw3, lb3, out);
}

// Round 6
// 591.000 us; speedup vs baseline: 1.0518x; 1.0518x over previous
//
#include <hip/hip_runtime.h>
#include <hip/hip_bf16.h>

namespace {
constexpr int kN    = 50000;
constexpr int kE    = 800000;
constexpr int kEtot = kE + kN;   // 850000 (self-loops appended)
constexpr int kEd   = 16;
constexpr int kH    = 8;
constexpr int kD    = 32;
constexpr int kC    = kH * kD;   // 256
constexpr int kNM   = 500;
constexpr int kNB   = (kN + 255) / 256;  // 196 scan blocks
constexpr int kCap  = 128;               // LDS softmax capacity (max deg ~45 here)
}

typedef __attribute__((ext_vector_type(8))) _Float16 half8;
typedef __attribute__((ext_vector_type(4))) float floatx4;

__device__ __forceinline__ float h2f(ushort u) {
  union { ushort u; _Float16 h; } v;
  v.u = u;
  return (float)v.h;
}
__device__ __forceinline__ ushort f2h(float f) {
  union { _Float16 h; ushort u; } v;
  v.h = (_Float16)f;  // v_cvt_f16_f32, RNE
  return v.u;
}

// ---------------- fused preprocessing: fp16 conversions + deg count + Q3 ----------------
// deg must be zeroed (hipMemsetAsync) before this launch.
__global__ void gat_pre(const float* __restrict__ x,
                        const float* __restrict__ W1, const float* __restrict__ W2,
                        const float* __restrict__ W3, const float* __restrict__ lw1,
                        const float* __restrict__ lw2,
                        ushort* __restrict__ xh, ushort* __restrict__ Wt1,
                        ushort* __restrict__ Wt2, ushort* __restrict__ Wt3,
                        ushort* __restrict__ lwt1, ushort* __restrict__ lwt2p,
                        const int* __restrict__ ei, int* __restrict__ deg,
                        const float* __restrict__ We1, const float* __restrict__ ae1,
                        const float* __restrict__ We2, const float* __restrict__ ae2,
                        const float* __restrict__ We3, const float* __restrict__ ae3,
                        float* __restrict__ Q3) {
  int i = blockIdx.x * blockDim.x + threadIdx.x;
  if (i < kN * 64) { xh[i] = f2h(x[i]); return; }
  i -= kN * 64;
  if (i < 256 * 64) {  // Wt1[n][k], W1 is 64x256
    int n = i >> 6, k = i & 63;
    Wt1[i] = f2h(W1[(long)k * 256 + n]);
    return;
  }
  i -= 256 * 64;
  if (i < 256 * 256) {
    int n = i >> 8, k = i & 255;
    Wt2[i] = f2h(W2[(long)k * 256 + n]);
    return;
  }
  i -= 256 * 256;
  if (i < 256 * 256) {
    int n = i >> 8, k = i & 255;
    Wt3[i] = f2h(W3[(long)k * 256 + n]);
    return;
  }
  i -= 256 * 256;
  if (i < 96 * 1024) {  // lwt1[n][k], lw1 is 1024x96
    int n = i >> 10, k = i & 1023;
    lwt1[i] = f2h(lw1[(long)k * 96 + n]);
    return;
  }
  i -= 96 * 1024;
  if (i < 64 * 128) {  // lwt2p[n][k], K zero-padded 96->128; lw2 is 96x64
    int n = i >> 7, k = i & 127;
    lwt2p[i] = (k < 96) ? f2h(lw2[(long)k * 64 + n]) : (ushort)0;
    return;
  }
  i -= 64 * 128;
  if (i < kE) {  // degree count
    atomicAdd(&deg[ei[kE + i]], 1);
    return;
  }
  i -= kE;
  if (i < 384) {  // Q3[l][c][h] = sum_d We_l[c, h*32+d] * ae_l[h,d]
    int l = i >> 7, r = i & 127;
    const float* We = (l == 0) ? We1 : (l == 1) ? We2 : We3;
    const float* ae = (l == 0) ? ae1 : (l == 1) ? ae2 : ae3;
    int c = r >> 3, h = r & 7;
    float s = 0.f;
#pragma unroll
    for (int d = 0; d < kD; d++) s += We[c * kC + h * kD + d] * ae[h * kD + d];
    Q3[l * 128 + c * kH + h] = s;
  }
}

// ---------------- CSR build (shared by all 3 layers) ----------------
// hierarchical scan of (deg[i]+1); also zeroes fillc (used later by gat_fill)
__global__ __launch_bounds__(256) void gat_scan_a(const int* __restrict__ deg,
                                                  int* __restrict__ offs,
                                                  int* __restrict__ bsum,
                                                  int* __restrict__ fillc) {
  __shared__ int s[256];
  int b = blockIdx.x, t = threadIdx.x;
  int i = b * 256 + t;
  int v = (i < kN) ? deg[i] + 1 : 0;
  if (i < kN) fillc[i] = 0;
  s[t] = v;
  __syncthreads();
  for (int o = 1; o < 256; o <<= 1) {
    int u = (t >= o) ? s[t - o] : 0;
    __syncthreads();
    s[t] += u;
    __syncthreads();
  }
  if (i < kN) offs[i] = s[t] - v;
  if (t == 255) bsum[b] = s[255];
}

// merged scan_b + scan_c: every block redundantly scans the 196 block sums (cheap),
// takes its own exclusive prefix, applies it to its 256 offs entries.
__global__ __launch_bounds__(256) void gat_scan_bc(int* __restrict__ offs,
                                                   const int* __restrict__ bsum) {
  __shared__ int s[256];
  int t = threadIdx.x;
  int v = (t < kNB) ? bsum[t] : 0;
  s[t] = v;
  __syncthreads();
  for (int o = 1; o < 256; o <<= 1) {
    int u = (t >= o) ? s[t - o] : 0;
    __syncthreads();
    s[t] += u;
    __syncthreads();
  }
  int excl = s[t] - v;
  __syncthreads();
  s[t] = excl;
  __syncthreads();
  int pre = s[blockIdx.x];
  int i = blockIdx.x * 256 + t;
  if (i < kN) offs[i] += pre;
  if (i == 0) offs[kN] = kEtot;
}

// CSR fill: el[pos]=edge id; sposA[n]=self-loop pos. ONE scattered 4B stream only
// (esrc is derived + written STREAMING in gat_aq -- halves scatter write-amp).
__global__ void gat_fill(const int* __restrict__ ei, const int* __restrict__ offs,
                         int* __restrict__ fillc, int* __restrict__ el,
                         int* __restrict__ sposA) {
  int e = blockIdx.x * blockDim.x + threadIdx.x;
  if (e >= kEtot) return;
  int d = (e < kE) ? ei[kE + e] : e - kE;
  int pos = offs[d] + atomicAdd(&fillc[d], 1);
  el[pos] = e;
  if (e >= kE) sposA[e - kE] = pos;
}

// aqX[pos*8+h] = ea[el[pos]] . Q_l[:,h]  for l=0..2 (CSR-ordered planes, fp16).
// Also derives esrc[pos] = ei[el[pos]] (4B L2-resident gather, streaming write).
// Thread = pos (STREAMING writes); ea read is a random 64B-line gather (no amplification).
// Self-loop slots get 0 (aggregate folds in the segment sum -- linearity of the dot).
__global__ __launch_bounds__(256) void gat_aq(const int* __restrict__ el,
                                              const int* __restrict__ ei,
                                              const float* __restrict__ ea,
                                              const float* __restrict__ Q3,
                                              int* __restrict__ esrc,
                                              ushort* __restrict__ aq0,
                                              ushort* __restrict__ aq1,
                                              ushort* __restrict__ aq2) {
  __shared__ float Qs[384];
  int t = threadIdx.x;
  for (int i = t; i < 384; i += 256) Qs[i] = Q3[i];
  __syncthreads();
  int pos = blockIdx.x * blockDim.x + t;
  if (pos >= kEtot) return;
  int e = el[pos];
  long base = (long)pos * kH;
  if (e >= kE) {
    esrc[pos] = e - kE;
    uint4 z = {0u, 0u, 0u, 0u};
    *(uint4*)(aq0 + base) = z;
    *(uint4*)(aq1 + base) = z;
    *(uint4*)(aq2 + base) = z;
    return;
  }
  esrc[pos] = ei[e];
  float eav[kEd];
#pragma unroll
  for (int q = 0; q < kEd / 4; q++) {
    float4 v = *(const float4*)(ea + (long)e * kEd + q * 4);
    eav[q * 4 + 0] = v.x; eav[q * 4 + 1] = v.y;
    eav[q * 4 + 2] = v.z; eav[q * 4 + 3] = v.w;
  }
  ushort* outp[3] = {aq0, aq1, aq2};
#pragma unroll
  for (int l = 0; l < 3; l++) {
    union { uint4 u; ushort us[8]; } o;
#pragma unroll
    for (int h = 0; h < kH; h++) {
      float q = 0.f;
#pragma unroll
      for (int c = 0; c < kEd; c++) q += eav[c] * Qs[l * 128 + c * kH + h];
      o.us[h] = f2h(q);
    }
    *(uint4*)(outp[l] + base) = o.u;
  }
}

// ---------------- fp16 MFMA GEMM (64M x 128N tile) ----------------
// Ch fp16 <- A(MxK,fp16 row-major) @ Bt^T  (layer GEMMs; always COEF epilogue)
// COEF: emit a_src[row,h]=xl_row_h . as_[h], a_dst likewise (N=256; 4 heads/block).
__global__ __launch_bounds__(256) void gat_gemm_mfma(
    int M, int K,
    const ushort* __restrict__ A0,
    const ushort* __restrict__ Bt,
    ushort* __restrict__ Ch, int ldch,
    const float* __restrict__ as_, const float* __restrict__ ad_,
    float* __restrict__ a_src, float* __restrict__ a_dst) {
  __shared__ ushort As[8][64][8];   // 8 KB
  __shared__ ushort Bs[8][128][8];  // 16 KB
  int t = threadIdx.x;
  int rowBase = blockIdx.y * 64;
  int colBase = blockIdx.x * 128;
  int w = t >> 6, L = t & 63;

  floatx4 acc[8];
#pragma unroll
  for (int i = 0; i < 8; i++) acc[i] = (floatx4){0.f, 0.f, 0.f, 0.f};

  int ar = t >> 2, akq = t & 3;  // A staging: row 0..63, k-chunk base
  int arow = rowBase + ar;
  int bn = t >> 1, bq2 = (t & 1) * 4;  // B staging: n 0..127, chunk half
  long brow = (long)(colBase + bn) * K;

  for (int k0 = 0; k0 < K; k0 += 64) {
#pragma unroll
    for (int half = 0; half < 2; half++) {
      int q = akq + half * 4;
      int gk = k0 + q * 8;
      uint4 av = {0u, 0u, 0u, 0u};
      if (arow < M) av = *(const uint4*)(A0 + (long)arow * K + gk);
      *(uint4*)&As[q][ar][0] = av;
    }
#pragma unroll
    for (int u = 0; u < 4; u++) {
      int q = bq2 + u;
      uint4 bv = *(const uint4*)(Bt + brow + k0 + q * 8);
      *(uint4*)&Bs[q][bn][0] = bv;
    }
    __syncthreads();
    int mrow = w * 16 + (L & 15);
    int nl = L & 15;
#pragma unroll
    for (int half = 0; half < 2; half++) {
      int q = (L >> 4) + half * 4;
      half8 af = *(const half8*)&As[q][mrow][0];
#pragma unroll
      for (int t8 = 0; t8 < 8; t8++) {
        half8 bf = *(const half8*)&Bs[q][t8 * 16 + nl][0];
        acc[t8] = __builtin_amdgcn_mfma_f32_16x16x32_f16(af, bf, acc[t8], 0, 0, 0);
      }
    }
    __syncthreads();
  }
  int nlo = L & 15;
  int rbase = rowBase + w * 16 + (L >> 4) * 4;
#pragma unroll
  for (int t8 = 0; t8 < 8; t8++) {
    int col = colBase + t8 * 16 + nlo;
#pragma unroll
    for (int r = 0; r < 4; r++) {
      int row = rbase + r;
      if (row >= M) continue;
      Ch[(long)row * ldch + col] = f2h(acc[t8][r]);
    }
  }
  {
    float ps[4][4], pd[4][4];
#pragma unroll
    for (int g = 0; g < 4; g++)
#pragma unroll
      for (int r = 0; r < 4; r++) { ps[g][r] = 0.f; pd[g][r] = 0.f; }
    int hA = colBase >> 5;
#pragma unroll
    for (int t8 = 0; t8 < 8; t8++) {
      int g = t8 >> 1;
      int widx = (t8 & 1) * 16 + nlo;
      float wsv = as_[(hA + g) * kD + widx];
      float wdv = ad_[(hA + g) * kD + widx];
#pragma unroll
      for (int r = 0; r < 4; r++) {
        ps[g][r] += acc[t8][r] * wsv;
        pd[g][r] += acc[t8][r] * wdv;
      }
    }
#pragma unroll
    for (int m = 1; m < 16; m <<= 1) {
#pragma unroll
      for (int g = 0; g < 4; g++)
#pragma unroll
        for (int r = 0; r < 4; r++) {
          ps[g][r] += __shfl_xor(ps[g][r], m);
          pd[g][r] += __shfl_xor(pd[g][r], m);
        }
    }
    if (nlo == 0) {
#pragma unroll
      for (int r = 0; r < 4; r++) {
        int row = rbase + r;
        if (row >= M) continue;
#pragma unroll
        for (int g = 0; g < 4; g++) {
          a_src[row * kH + hA + g] = ps[g][r];
          a_dst[row * kH + hA + g] = pd[g][r];
        }
      }
    }
  }
}

// ---------------- fused logits + segment-softmax + aggregation ----------------
// one wave per node. Logit a = leaky(a_src[src,h] + a_dst[n,h] + aq[pos,h]).
// Self-loop aq (= segment sum of aq, via linearity) is folded in here: aq self slots
// hold 0, phase 1 accumulates sq = sum_j aq[j,h] and fixes the self slot's logit.
__global__ __launch_bounds__(256, 8) void gat_aggregate(
    const int* __restrict__ offs, const int* __restrict__ esrc,
    const int* __restrict__ sposA,
    const ushort* __restrict__ aq,
    const float* __restrict__ a_src, const float* __restrict__ a_dst,
    const ushort* __restrict__ xlh, const float* __restrict__ bias,
    ushort* __restrict__ hh) {
  __shared__ float alf[4][kCap][kH];  // 16 KB
  __shared__ int srcs[4][kCap];       // 2 KB
  int wid = threadIdx.x >> 6;
  int n = blockIdx.x * 4 + wid;  // grid is exact: kN % 4 == 0
  int L = threadIdx.x & 63;
  int lo = offs[n], hi = offs[n + 1];
  int deg = hi - lo;
  bool fits = (deg <= kCap);
  int spos = sposA[n];  // CSR position of n's self-loop
  int hp = L & 7, sl = L >> 3;
  float adr = a_dst[n * kH + hp];
  float m = -1e30f;
  float sq = 0.f;
  if (fits) {
    for (int j = lo + sl; j < hi; j += 8) {
      int sidx = esrc[j];
      float aqv = h2f(aq[(long)j * kH + hp]);
      sq += aqv;
      float a = a_src[sidx * kH + hp] + adr + aqv;
      a = a > 0.f ? a : 0.2f * a;
      alf[wid][j - lo][hp] = a;
      if (hp == 0) srcs[wid][j - lo] = sidx;
      m = fmaxf(m, a);
    }
  } else {
    for (int j = lo + sl; j < hi; j += 8) {
      float aqv = h2f(aq[(long)j * kH + hp]);
      sq += aqv;
      float a = a_src[esrc[j] * kH + hp] + adr + aqv;
      a = a > 0.f ? a : 0.2f * a;
      m = fmaxf(m, a);
    }
  }
#pragma unroll
  for (int msk = 8; msk < 64; msk <<= 1) {
    m = fmaxf(m, __shfl_xor(m, msk));
    sq += __shfl_xor(sq, msk);
  }
  // self-loop logit: src = n, aq_self = sq (self slot held 0, so sq is the edge sum)
  float aself = a_src[n * kH + hp] + adr + sq;
  aself = aself > 0.f ? aself : 0.2f * aself;
  m = fmaxf(m, aself);
  if (fits && sl == 0) alf[wid][spos - lo][hp] = aself;  // same-wave overwrite, ordered
  __syncthreads();
  float s = 0.f;
  if (fits) {
    for (int j = lo + sl; j < hi; j += 8) {
      float pp = __expf(alf[wid][j - lo][hp] - m);
      alf[wid][j - lo][hp] = pp;
      s += pp;
    }
  } else {
    for (int j = lo + sl; j < hi; j += 8) {
      float aqv = (j == spos) ? sq : h2f(aq[(long)j * kH + hp]);
      float a = a_src[esrc[j] * kH + hp] + adr + aqv;
      a = a > 0.f ? a : 0.2f * a;
      s += __expf(a - m);
    }
  }
#pragma unroll
  for (int msk = 8; msk < 64; msk <<= 1) s += __shfl_xor(s, msk);
  __syncthreads();
  // ---- main: half-wave per edge, 4 edges x 2 half-waves per iter ----
  int eh = L >> 5;
  int cl = L & 31;
  int c = cl * 8;
  int h = cl >> 2;
  float invs = 1.f / __shfl(s, h);
  float mh = __shfl(m, h);
  float acc[8] = {0.f, 0.f, 0.f, 0.f, 0.f, 0.f, 0.f, 0.f};
  union { uint4 u; _Float16 hf[8]; } v0, v1, v2, v3;
  if (fits) {
    int j = lo;
    for (; j + 8 <= hi; j += 8) {
      int j0 = j + eh, j1 = j + 2 + eh, j2 = j + 4 + eh, j3 = j + 6 + eh;
      int s0 = srcs[wid][j0 - lo];
      int s1 = srcs[wid][j1 - lo];
      int s2 = srcs[wid][j2 - lo];
      int s3 = srcs[wid][j3 - lo];
      float t0 = alf[wid][j0 - lo][h];
      float t1 = alf[wid][j1 - lo][h];
      float t2 = alf[wid][j2 - lo][h];
      float t3 = alf[wid][j3 - lo][h];
      v0.u = *(const uint4*)(xlh + (long)s0 * kC + c);
      v1.u = *(const uint4*)(xlh + (long)s1 * kC + c);
      v2.u = *(const uint4*)(xlh + (long)s2 * kC + c);
      v3.u = *(const uint4*)(xlh + (long)s3 * kC + c);
#pragma unroll
      for (int i = 0; i < 8; i++) acc[i] += t0 * (float)v0.hf[i];
#pragma unroll
      for (int i = 0; i < 8; i++) acc[i] += t1 * (float)v1.hf[i];
#pragma unroll
      for (int i = 0; i < 8; i++) acc[i] += t2 * (float)v2.hf[i];
#pragma unroll
      for (int i = 0; i < 8; i++) acc[i] += t3 * (float)v3.hf[i];
    }
    for (; j < hi; j += 2) {
      int jj = j + eh;
      bool valid = jj < hi;
      int idx = valid ? jj - lo : 0;
      int sn = srcs[wid][idx];
      float att = valid ? alf[wid][idx][h] : 0.f;
      v0.u = *(const uint4*)(xlh + (long)sn * kC + c);
#pragma unroll
      for (int i = 0; i < 8; i++) acc[i] += att * (float)v0.hf[i];
    }
  } else {
    float adh = a_dst[n * kH + h];
    float sqh = __shfl(sq, h);
    for (int j = lo; j < hi; j += 2) {
      int jj = j + eh;
      bool valid = jj < hi;
      int js = valid ? jj : lo;
      int sn = esrc[js];
      float aqv = (js == spos) ? sqh : h2f(aq[(long)js * kH + h]);
      float a = a_src[sn * kH + h] + adh + aqv;
      a = a > 0.f ? a : 0.2f * a;
      float att = valid ? __expf(a - mh) : 0.f;
      v0.u = *(const uint4*)(xlh + (long)sn * kC + c);
#pragma unroll
      for (int i = 0; i < 8; i++) acc[i] += att * (float)v0.hf[i];
    }
  }
#pragma unroll
  for (int i = 0; i < 8; i++) acc[i] += __shfl_xor(acc[i], 32);
  if (eh == 0) {
    float4 b0 = *(const float4*)(bias + c);
    float4 b1 = *(const float4*)(bias + c + 4);
    ushort o[8];
    o[0] = f2h(acc[0] * invs + b0.x); o[1] = f2h(acc[1] * invs + b0.y);
    o[2] = f2h(acc[2] * invs + b0.z); o[3] = f2h(acc[3] * invs + b0.w);
    o[4] = f2h(acc[4] * invs + b1.x); o[5] = f2h(acc[5] * invs + b1.y);
    o[6] = f2h(acc[6] * invs + b1.z); o[7] = f2h(acc[7] * invs + b1.w);
    *(uint4*)(hh + (long)n * kC + c) = *(uint4*)o;
  }
}

// ---------------- pooling: 1024 threads = 4 row-groups x 256 channels ----------------
__global__ __launch_bounds__(1024) void gat_pool(const ushort* __restrict__ h3h,
                                                 const int* __restrict__ batch,
                                                 ushort* __restrict__ hpoolh) {
  __shared__ float red[3][256];
  int m = blockIdx.x;
  int c = threadIdx.x & 255;
  int g = threadIdx.x >> 8;  // 0..3
  int lo = 0, hi = kN;
  while (lo < hi) { int mid = (lo + hi) >> 1; if (batch[mid] < m) lo = mid + 1; else hi = mid; }
  int start = lo;
  hi = kN;
  while (lo < hi) { int mid = (lo + hi) >> 1; if (batch[mid] < m + 1) lo = mid + 1; else hi = mid; }
  int end = lo;
  float s0 = 0.f, s1 = 0.f, s2 = 0.f, s3 = 0.f;
  int n = start + g;
  for (; n + 12 < end; n += 16) {
    s0 += h2f(h3h[(long)n * kC + c]);
    s1 += h2f(h3h[(long)(n + 4) * kC + c]);
    s2 += h2f(h3h[(long)(n + 8) * kC + c]);
    s3 += h2f(h3h[(long)(n + 12) * kC + c]);
  }
  for (; n < end; n += 4) s0 += h2f(h3h[(long)n * kC + c]);
  float s = (s0 + s1) + (s2 + s3);
  if (g > 0) red[g - 1][c] = s;
  __syncthreads();
  if (g == 0)
    hpoolh[(long)m * kC + c] = f2h(s + red[0][c] + red[1][c] + red[2][c]);
}

// ---------------- fused 3-stage MLP ----------------
// stage1: leaky( concat[h1,h2,h3,hpool[batch]] @ lwt1^T + lb1 ) -> C1s (LDS, fp16, 64x128, cols 96+ = 0)
// stage2: leaky( C1s @ lwt2p^T + lb2 ), dot with lw3, + lb3, sigmoid -> out[row]
// LDS ALIASED: C1s reuses As+Bs (dead after stage-1 loop's final barrier). 56KB -> 40KB
// => 4 blocks/CU (was 2). Stage-1 MFMA skips cols 96..127 (structurally zero).
__global__ __launch_bounds__(256) void gat_mlp(
    const ushort* __restrict__ h1h, const ushort* __restrict__ h2h,
    const ushort* __restrict__ h3h, const ushort* __restrict__ hpoolh,
    const int* __restrict__ batch,
    const ushort* __restrict__ lwt1, const float* __restrict__ lb1,
    const ushort* __restrict__ lwt2p, const float* __restrict__ lb2,
    const float* __restrict__ lw3, const float* __restrict__ lb3,
    float* __restrict__ out) {
  __shared__ __align__(16) char smem[40960];
  auto As  = (ushort(*)[64][8])(smem);            // [8][64][8]   8 KB
  auto Bs  = (ushort(*)[128][8])(smem + 8192);    // [8][128][8] 16 KB
  auto C1s = (ushort(*)[64][8])(smem);            // [16][64][8] 16 KB (aliases As+Bs[0:8K])
  auto B2s = (ushort(*)[64][8])(smem + 24576);    // [16][64][8] 16 KB
  constexpr int K = 1024;
  int t = threadIdx.x;
  int rowBase = blockIdx.x * 64;
  int w = t >> 6, L = t & 63;

  floatx4 acc[8];
#pragma unroll
  for (int i = 0; i < 8; i++) acc[i] = (floatx4){0.f, 0.f, 0.f, 0.f};

  int ar = t >> 2, akq = t & 3;
  int arow = rowBase + ar;
  int bn = t >> 1, bq2 = (t & 1) * 4;
  bool bok = bn < 96;
  long brow = (long)bn * K;

  for (int k0 = 0; k0 < K; k0 += 64) {
#pragma unroll
    for (int half = 0; half < 2; half++) {
      int q = akq + half * 4;
      int gk = k0 + q * 8;
      uint4 av = {0u, 0u, 0u, 0u};
      if (arow < kN) {
        int j = gk >> 8, kc = gk & 255;
        const ushort* src = (j == 0) ? h1h : (j == 1) ? h2h : (j == 2) ? h3h : hpoolh;
        long rr = (j == 3) ? (long)batch[arow] : (long)arow;
        av = *(const uint4*)(src + rr * 256 + kc);
      }
      *(uint4*)&As[q][ar][0] = av;
    }
    if (bok) {
#pragma unroll
      for (int u = 0; u < 4; u++) {
        int q = bq2 + u;
        uint4 bv = *(const uint4*)(lwt1 + brow + k0 + q * 8);
        *(uint4*)&Bs[q][bn][0] = bv;
      }
    }
    __syncthreads();
    int mrow = w * 16 + (L & 15);
    int nl = L & 15;
#pragma unroll
    for (int half = 0; half < 2; half++) {
      int q = (L >> 4) + half * 4;
      half8 af = *(const half8*)&As[q][mrow][0];
#pragma unroll
      for (int t8 = 0; t8 < 6; t8++) {  // cols 96..127 are zero -> skip 2/8 MFMA
        half8 bf = *(const half8*)&Bs[q][t8 * 16 + nl][0];
        acc[t8] = __builtin_amdgcn_mfma_f32_16x16x32_f16(af, bf, acc[t8], 0, 0, 0);
      }
    }
    __syncthreads();
  }
  // stage-1 epilogue -> C1s (aliases As/Bs; all waves are past the final barrier).
  // cols >= 96: acc stayed 0, lb1 treated 0 -> stays 0 (needed as K-padding for stage 2).
  int nlo = L & 15;
  int lrbase = w * 16 + (L >> 4) * 4;
#pragma unroll
  for (int t8 = 0; t8 < 8; t8++) {
    int col = t8 * 16 + nlo;  // 0..127
    float bv = (col < 96) ? lb1[col] : 0.f;
#pragma unroll
    for (int r = 0; r < 4; r++) {
      float v = acc[t8][r] + bv;
      v = v > 0.f ? v : 0.01f * v;
      C1s[col >> 3][lrbase + r][col & 7] = f2h(v);
    }
  }
  // stage-2 B: lwt2p is [64 n][128 k] (B2s does not alias As/Bs/C1s)
  {
    int n2 = t >> 2, u0 = (t & 3) * 4;
#pragma unroll
    for (int u = 0; u < 4; u++) {
      int q = u0 + u;
      *(uint4*)&B2s[q][n2][0] = *(const uint4*)(lwt2p + (long)n2 * 128 + q * 8);
    }
  }
  __syncthreads();
  // stage-2 MFMA: 64 rows x 64 cols, K=128 in 4 K-32 steps.
  // FRAGMENT LAYOUT: lane-group (L>>4) must hold k-chunk (L>>4)+ks*4 -- same as stage 1.
  floatx4 acc2[4];
#pragma unroll
  for (int i = 0; i < 4; i++) acc2[i] = (floatx4){0.f, 0.f, 0.f, 0.f};
  {
    int mrow = w * 16 + (L & 15);
    int nl = L & 15;
#pragma unroll
    for (int ks = 0; ks < 4; ks++) {
      int q = (L >> 4) + ks * 4;
      half8 af = *(const half8*)&C1s[q][mrow][0];
#pragma unroll
      for (int nf = 0; nf < 4; nf++) {
        half8 bf = *(const half8*)&B2s[q][nf * 16 + nl][0];
        acc2[nf] = __builtin_amdgcn_mfma_f32_16x16x32_f16(af, bf, acc2[nf], 0, 0, 0);
      }
    }
  }
  // stage-2 epilogue: leaky(.+lb2) . lw3 + lb3 -> sigmoid -> out
  {
    float dot[4] = {0.f, 0.f, 0.f, 0.f};
#pragma unroll
    for (int nf = 0; nf < 4; nf++) {
      int col = nf * 16 + nlo;  // 0..63
      float bv = lb2[col];
      float wv = lw3[col];
#pragma unroll
      for (int r = 0; r < 4; r++) {
        float v = acc2[nf][r] + bv;
        v = v > 0.f ? v : 0.01f * v;
        dot[r] += v * wv;
      }
    }
#pragma unroll
    for (int msk = 1; msk < 16; msk <<= 1)
#pragma unroll
      for (int r = 0; r < 4; r++) dot[r] += __shfl_xor(dot[r], msk);
    if (nlo == 0) {
      float b3 = lb3[0];
#pragma unroll
      for (int r = 0; r < 4; r++) {
        int row = rowBase + lrbase + r;
        if (row < kN) out[row] = 1.f / (1.f + __expf(-(dot[r] + b3)));
      }
    }
  }
}

// ---------------- host ----------------
static inline int cdiv(int a, int b) { return (a + b - 1) / b; }

extern "C" void kernel_launch(void* const* d_in, const int* in_sizes, int n_in,
                              void* d_out, int out_size, void* d_ws, size_t ws_size,
                              hipStream_t stream) {
  (void)in_sizes; (void)n_in; (void)out_size; (void)ws_size;
  const float* x = (const float*)d_in[0];
  const int* ei = (const int*)d_in[1];
  const float* ea = (const float*)d_in[2];
  const int* batch = (const int*)d_in[3];
  const float *W[3], *as_[3], *ad_[3], *We_[3], *ae_[3], *bb[3];
  for (int l = 0; l < 3; l++) {
    W[l]   = (const float*)d_in[4 + 6 * l];
    as_[l] = (const float*)d_in[5 + 6 * l];
    ad_[l] = (const float*)d_in[6 + 6 * l];
    We_[l] = (const float*)d_in[7 + 6 * l];
    ae_[l] = (const float*)d_in[8 + 6 * l];
    bb[l]  = (const float*)d_in[9 + 6 * l];
  }
  const float* lw1 = (const float*)d_in[22];
  const float* lb1 = (const float*)d_in[23];
  const float* lw2 = (const float*)d_in[24];
  const float* lb2 = (const float*)d_in[25];
  const float* lw3 = (const float*)d_in[26];
  const float* lb3 = (const float*)d_in[27];
  float* out = (float*)d_out;

  char* p = (char*)d_ws;
  auto carve = [&](size_t bytes) -> void* {
    void* r = (void*)p;
    p += (bytes + 255) & ~(size_t)255;
    return r;
  };
  ushort* aq0    = (ushort*)carve(sizeof(ushort) * (size_t)kEtot * kH);
  ushort* aq1    = (ushort*)carve(sizeof(ushort) * (size_t)kEtot * kH);
  ushort* aq2    = (ushort*)carve(sizeof(ushort) * (size_t)kEtot * kH);
  float* a_src   = (float*)carve(sizeof(float) * (size_t)kN * kH);
  float* a_dst   = (float*)carve(sizeof(float) * (size_t)kN * kH);
  float* Q3      = (float*)carve(sizeof(float) * 3 * 128);
  ushort* xh     = (ushort*)carve(sizeof(ushort) * (size_t)kN * 64);
  ushort* xlh    = (ushort*)carve(sizeof(ushort) * (size_t)kN * kC);
  ushort* h1h    = (ushort*)carve(sizeof(ushort) * (size_t)kN * kC);
  ushort* h2h    = (ushort*)carve(sizeof(ushort) * (size_t)kN * kC);
  ushort* h3h    = (ushort*)carve(sizeof(ushort) * (size_t)kN * kC);
  ushort* hpoolh = (ushort*)carve(sizeof(ushort) * (size_t)kNM * kC);
  ushort* Wt1    = (ushort*)carve(sizeof(ushort) * 64 * 256);
  ushort* Wt2    = (ushort*)carve(sizeof(ushort) * 256 * 256);
  ushort* Wt3    = (ushort*)carve(sizeof(ushort) * 256 * 256);
  ushort* lwt1   = (ushort*)carve(sizeof(ushort) * 1024 * 96);
  ushort* lwt2p  = (ushort*)carve(sizeof(ushort) * 64 * 128);
  int* deg   = (int*)carve(sizeof(int) * kN);
  int* fillc = (int*)carve(sizeof(int) * kN);
  int* offs  = (int*)carve(sizeof(int) * (kN + 1));
  int* bsum  = (int*)carve(sizeof(int) * 256);
  int* el    = (int*)carve(sizeof(int) * kEtot);
  int* esrc  = (int*)carve(sizeof(int) * kEtot);
  int* sposA = (int*)carve(sizeof(int) * kN);

  // ---- zero deg (driver-side) + fused conversions/count/Q ----
  hipMemsetAsync(deg, 0, sizeof(int) * kN, stream);
  {
    int tot = kN * 64 + 256 * 64 + 2 * 256 * 256 + 96 * 1024 + 64 * 128 + kE + 384;
    gat_pre<<<cdiv(tot, 256), 256, 0, stream>>>(
        x, W[0], W[1], W[2], lw1, lw2, xh, Wt1, Wt2, Wt3, lwt1, lwt2p,
        ei, deg, We_[0], ae_[0], We_[1], ae_[1], We_[2], ae_[2], Q3);
  }

  // ---- CSR build + edge-coefficient precompute (all 3 layers at once) ----
  gat_scan_a<<<kNB, 256, 0, stream>>>(deg, offs, bsum, fillc);
  gat_scan_bc<<<kNB, 256, 0, stream>>>(offs, bsum);
  gat_fill<<<cdiv(kEtot, 256), 256, 0, stream>>>(ei, offs, fillc, el, sposA);
  gat_aq<<<cdiv(kEtot, 256), 256, 0, stream>>>(el, ei, ea, Q3, esrc, aq0, aq1, aq2);

  // ---- 3 GAT layers ----
  const ushort* hinh[3] = {xh, h1h, h2h};
  ushort* houth[3] = {h1h, h2h, h3h};
  const ushort* Wt[3] = {Wt1, Wt2, Wt3};
  const ushort* aqP[3] = {aq0, aq1, aq2};
  int kdim[3] = {64, kC, kC};
  for (int l = 0; l < 3; l++) {
    dim3 ggrid(kC / 128, cdiv(kN, 64));
    gat_gemm_mfma<<<ggrid, 256, 0, stream>>>(
        kN, kdim[l], hinh[l], Wt[l], xlh, kC,
        as_[l], ad_[l], a_src, a_dst);
    gat_aggregate<<<kN / 4, 256, 0, stream>>>(offs, esrc, sposA, aqP[l], a_src, a_dst,
                                              xlh, bb[l], houth[l]);
  }

  // ---- pooling ----
  gat_pool<<<kNM, 1024, 0, stream>>>(h3h, batch, hpoolh);

  // ---- fused MLP (all 3 layers + sigmoid, one launch) ----
  gat_mlp<<<cdiv(kN, 64), 256, 0, stream>>>(
      h1h, h2h, h3h, hpoolh, batch,
      lwt1, lb1, lwt2p, lb2, lw3, lb3, out);
}